// Round 4
// baseline (410.823 us; speedup 1.0000x reference)
//
#include <hip/hip_runtime.h>
#include <hip/hip_bf16.h>

typedef __bf16 bf16x8 __attribute__((ext_vector_type(8)));
typedef float f32x4 __attribute__((ext_vector_type(4)));

#define LR_SLOPE 0.2f
#define NBKMAX 256          // buckets of 512 nodes -> supports N <= 131072

static __device__ __forceinline__ unsigned short f2bf(float f){
  union { float f; unsigned u; } v; v.f = f;
  unsigned u = v.u;
  u += 0x7fffu + ((u >> 16) & 1u);
  return (unsigned short)(u >> 16);
}
static __device__ __forceinline__ float bf2f(unsigned short us){
  union { unsigned u; float f; } v; v.u = ((unsigned)us) << 16;
  return v.f;
}
static __device__ __forceinline__ unsigned pk2(float a, float b){
  return (unsigned)f2bf(a) | ((unsigned)f2bf(b) << 16);
}
// OCP e4m3 via gfx950 HW converts
static __device__ __forceinline__ unsigned char f2e4m3(float f){
  return (unsigned char)(__builtin_amdgcn_cvt_pk_fp8_f32(f, 0.f, 0, false) & 0xff);
}
static __device__ __forceinline__ float e4m32f(unsigned b){
  return __builtin_amdgcn_cvt_f32_fp8(b, 0);
}

// ---------------- weight prep: transpose + bf16 ----------------
__global__ void prep_w1_kernel(const float* __restrict__ W1, unsigned short* __restrict__ wt1){
  int t = blockIdx.x*256 + threadIdx.x;
  if (t >= 512*64) return;
  int k = t >> 6, n = t & 63;
  wt1[n*512 + k] = f2bf(W1[t]);
}

__global__ void prep_w2_kernel(const float* __restrict__ W2, unsigned short* __restrict__ wt2){
  int t = blockIdx.x*256 + threadIdx.x;
  if (t >= 48*64) return;
  int c = t >> 6, k = t & 63;
  wt2[t] = (c < 40) ? f2bf(W2[k*40 + c]) : (unsigned short)0;
}

// ---------------- GEMM1: h1[N,64] = x[N,512] @ W1 (bf16 MFMA, fp8 out) ----------------
__global__ __launch_bounds__(256) void gemm1_kernel(
    const float* __restrict__ x, const unsigned short* __restrict__ wt1,
    unsigned char* __restrict__ h1f8, int N)
{
  __shared__ unsigned short Alds[64*72];
  const int tid = threadIdx.x;
  const int wv = tid >> 6, lane = tid & 63;
  const int c0 = lane & 15, g = lane >> 4;
  const int rowbase = blockIdx.x * 64;

  const int sr = tid >> 2, sq = tid & 3;
  const int grow = rowbase + sr;
  const bool rv = grow < N;
  const float* xp = x + (size_t)grow*512 + sq*16;
  unsigned short* wls = Alds + sr*72 + sq*16;

  f32x4 acc[4];
  acc[0] = acc[1] = acc[2] = acc[3] = (f32x4){0.f,0.f,0.f,0.f};

  const unsigned short* bp0 = wt1 + (size_t)(wv*16 + c0)*512 + g*8;

  for (int kt = 0; kt < 8; ++kt){
    float4 f0 = {0,0,0,0}, f1 = {0,0,0,0}, f2 = {0,0,0,0}, f3 = {0,0,0,0};
    if (rv){
      const float4* p = (const float4*)(xp + kt*64);
      f0 = p[0]; f1 = p[1]; f2 = p[2]; f3 = p[3];
    }
    uint4 w0 = { pk2(f0.x,f0.y), pk2(f0.z,f0.w), pk2(f1.x,f1.y), pk2(f1.z,f1.w) };
    uint4 w1 = { pk2(f2.x,f2.y), pk2(f2.z,f2.w), pk2(f3.x,f3.y), pk2(f3.z,f3.w) };
    if (kt) __syncthreads();
    *(uint4*)wls       = w0;
    *(uint4*)(wls + 8) = w1;
    __syncthreads();
    bf16x8 b0 = *(const bf16x8*)(bp0 + kt*64);
    bf16x8 b1 = *(const bf16x8*)(bp0 + kt*64 + 32);
    #pragma unroll
    for (int mi = 0; mi < 4; ++mi){
      const unsigned short* ap = Alds + (mi*16 + c0)*72 + g*8;
      bf16x8 a0 = *(const bf16x8*)ap;
      bf16x8 a1 = *(const bf16x8*)(ap + 32);
      acc[mi] = __builtin_amdgcn_mfma_f32_16x16x32_bf16(a0, b0, acc[mi], 0,0,0);
      acc[mi] = __builtin_amdgcn_mfma_f32_16x16x32_bf16(a1, b1, acc[mi], 0,0,0);
    }
  }
  #pragma unroll
  for (int mi = 0; mi < 4; ++mi){
    #pragma unroll
    for (int i = 0; i < 4; ++i){
      int row = rowbase + mi*16 + 4*g + i;
      if (row < N) h1f8[(size_t)row*64 + wv*16 + c0] = f2e4m3(acc[mi][i]);
    }
  }
}

// ---------------- attn1: per (node,head) dot with att vectors ----------------
__global__ void attn1_kernel(const unsigned char* __restrict__ h1f8,
    const float* __restrict__ aw_s, const float* __restrict__ aw_d,
    float* __restrict__ as1, float* __restrict__ ad1, int N)
{
  int t = blockIdx.x*256 + threadIdx.x;
  if (t >= N*8) return;
  int h = t & 7;
  uint2 hv = *(const uint2*)(h1f8 + (size_t)t*8);   // 8 fp8
  float f[8];
  f[0] = __builtin_amdgcn_cvt_f32_fp8(hv.x, 0);
  f[1] = __builtin_amdgcn_cvt_f32_fp8(hv.x, 1);
  f[2] = __builtin_amdgcn_cvt_f32_fp8(hv.x, 2);
  f[3] = __builtin_amdgcn_cvt_f32_fp8(hv.x, 3);
  f[4] = __builtin_amdgcn_cvt_f32_fp8(hv.y, 0);
  f[5] = __builtin_amdgcn_cvt_f32_fp8(hv.y, 1);
  f[6] = __builtin_amdgcn_cvt_f32_fp8(hv.y, 2);
  f[7] = __builtin_amdgcn_cvt_f32_fp8(hv.y, 3);
  const float* ws = aw_s + h*8;
  const float* wd = aw_d + h*8;
  float s = 0.f, d = 0.f;
  #pragma unroll
  for (int j = 0; j < 8; ++j){
    s = fmaf(f[j], ws[j], s);
    d = fmaf(f[j], wd[j], d);
  }
  as1[t] = s; ad1[t] = d;
}

// ---------------- CSR build: histogram + scan ----------------
__global__ void init_deg_kernel(int* __restrict__ deg, int N){
  int t = blockIdx.x*256 + threadIdx.x;
  if (t < N) deg[t] = 1;
}

__global__ void hist_kernel(const int* __restrict__ ei, int* __restrict__ deg, int E){
  int t = blockIdx.x*256 + threadIdx.x;
  if (t < E) atomicAdd(&deg[ei[E + t]], 1);
}

__global__ void scan1_kernel(const int* __restrict__ deg, int* __restrict__ rowstart,
                             int* __restrict__ partial, int N){
  __shared__ int sc[256];
  int t = threadIdx.x;
  int base = blockIdx.x*1024 + t*4;
  int d0=0,d1=0,d2=0,d3=0;
  if (base + 3 < N){
    int4 v = *(const int4*)(deg + base);
    d0=v.x; d1=v.y; d2=v.z; d3=v.w;
  } else {
    if (base   < N) d0 = deg[base];
    if (base+1 < N) d1 = deg[base+1];
    if (base+2 < N) d2 = deg[base+2];
    if (base+3 < N) d3 = deg[base+3];
  }
  int s = d0+d1+d2+d3;
  sc[t] = s; __syncthreads();
  for (int off = 1; off < 256; off <<= 1){
    int v = (t >= off) ? sc[t-off] : 0;
    __syncthreads();
    if (t >= off) sc[t] += v;
    __syncthreads();
  }
  int excl = sc[t] - s;
  if (base   < N) rowstart[base]   = excl;
  if (base+1 < N) rowstart[base+1] = excl + d0;
  if (base+2 < N) rowstart[base+2] = excl + d0 + d1;
  if (base+3 < N) rowstart[base+3] = excl + d0 + d1 + d2;
  if (t == 255) partial[blockIdx.x] = sc[255];
}

__global__ void scan2_kernel(int* __restrict__ partial, int NB){
  __shared__ int sc[128];
  int t = threadIdx.x;
  int v = (t < NB) ? partial[t] : 0;
  sc[t] = v; __syncthreads();
  for (int off = 1; off < 128; off <<= 1){
    int u = (t >= off) ? sc[t-off] : 0;
    __syncthreads();
    if (t >= off) sc[t] += u;
    __syncthreads();
  }
  if (t < NB) partial[t] = sc[t] - v;
  if (t == 127) partial[NB] = sc[127];
}

__global__ void scan3_kernel(int* __restrict__ rowstart,
                             const int* __restrict__ partial, int N, int NB){
  int t = blockIdx.x*256 + threadIdx.x;
  if (t < N) rowstart[t] = rowstart[t] + partial[t >> 10];
  if (t == 0) rowstart[N] = partial[NB];
}

__global__ void init_bcur_kernel(const int* __restrict__ rowstart, int* __restrict__ bcur, int NBK){
  int t = threadIdx.x;
  if (t < NBK) bcur[t] = rowstart[t << 9];
}

// ---------------- bucket phase A ----------------
__global__ __launch_bounds__(256) void bucketA_kernel(
    const int* __restrict__ ei, int* __restrict__ bcur,
    unsigned* __restrict__ bucketed, int E, int M, int NBK)
{
  __shared__ int hist[NBKMAX];
  __shared__ int gb[NBKMAX];
  const int tid = threadIdx.x;
  const int t0 = blockIdx.x * 2048;
  for (int i = tid; i < NBK; i += 256) hist[i] = 0;
  __syncthreads();

  unsigned pe[8]; int bk[8], rnk[8];
  #pragma unroll
  for (int j = 0; j < 8; ++j){
    int m = t0 + j*256 + tid;
    if (m < M){
      int s, d;
      if (m < E){ s = ei[m]; d = ei[E + m]; }
      else      { s = d = m - E; }
      bk[j] = d >> 9;
      pe[j] = ((unsigned)s << 9) | (unsigned)(d & 511);
      rnk[j] = atomicAdd(&hist[bk[j]], 1);
    } else bk[j] = -1;
  }
  __syncthreads();
  for (int i = tid; i < NBK; i += 256) gb[i] = atomicAdd(&bcur[i], hist[i]);
  __syncthreads();
  #pragma unroll
  for (int j = 0; j < 8; ++j){
    if (bk[j] >= 0) bucketed[gb[bk[j]] + rnk[j]] = pe[j];
  }
}

// ---------------- bucket phase B ----------------
__global__ __launch_bounds__(512) void bucketB_kernel(
    const unsigned* __restrict__ bucketed, const int* __restrict__ rowstart,
    int* __restrict__ csr, int N)
{
  __shared__ int cur[512];
  const int k = blockIdx.x;
  const int nodebase = k << 9;
  const int nn = min(512, N - nodebase);
  for (int i = threadIdx.x; i < nn; i += 512) cur[i] = rowstart[nodebase + i];
  __syncthreads();
  const int lo = rowstart[nodebase];
  const int hi = rowstart[nodebase + nn];
  for (int m = lo + threadIdx.x; m < hi; m += 512){
    unsigned e = bucketed[m];
    int pos = atomicAdd(&cur[e & 511], 1);
    csr[pos] = (int)(e >> 9);
  }
}

// ---------------- layer-1 aggregation (fp8 gather, 1 line/edge) ----------------
__global__ void l1agg_kernel(const int* __restrict__ rowstart, const int* __restrict__ csr,
    const float* __restrict__ as1, const float* __restrict__ ad1,
    const unsigned char* __restrict__ h1f8, const float* __restrict__ b1,
    unsigned short* __restrict__ g1b, int N)
{
  int wid = blockIdx.x*4 + (threadIdx.x >> 6);
  if (wid >= N) return;
  const int lane = threadIdx.x & 63;
  const int hf = lane >> 3;          // head for the feature role
  const int jq = lane >> 3;          // edge-in-chunk for the weight role
  const int hq = lane & 7;           // head for the weight role
  int r0 = rowstart[wid], r1 = rowstart[wid+1];
  int cnt = r1 - r0;
  int cap = cnt < 64 ? cnt : 64;
  float advv = ad1[wid*8 + hq];
  float acc = 0.f, den = 0.f;

  int myidx = csr[r0 + (lane < cap ? lane : cap-1)];

  int sw = __shfl(myidx, jq < cap ? jq : cap-1);
  float ev = as1[sw*8 + hq];

  for (int c = 0; c < cap; c += 8){
    float evn = 0.f;
    if (c + 8 < cap){
      int cj = c + 8 + jq;
      int swn = __shfl(myidx, cj < cap ? cj : cap-1);
      evn = as1[swn*8 + hq];
    }
    float t = ev + advv;
    t = (t > 0.f) ? t : LR_SLOPE*t;
    float w = __expf(t);
    if (c + jq >= cap) w = 0.f;
    #pragma unroll
    for (int j = 0; j < 8; ++j){
      if (c + j < cap){                            // wave-uniform guard
        float wj = __shfl(w, j*8 + hf);
        den += wj;
        int sj = __shfl(myidx, c + j);
        acc = fmaf(wj, e4m32f(h1f8[(size_t)sj*64 + lane]), acc);
      }
    }
    ev = evn;
  }
  for (int r = r0 + 64; r < r1; ++r){             // degree>64 fallback
    int sx = csr[r];
    float t = as1[sx*8 + hf] + ad1[wid*8 + hf];
    t = (t > 0.f) ? t : LR_SLOPE*t;
    float w = __expf(t);
    den += w;
    acc = fmaf(w, e4m32f(h1f8[(size_t)sx*64 + lane]), acc);
  }
  float vv = acc/den + b1[lane];
  vv = (vv > 0.f) ? vv : (__expf(vv) - 1.f);      // ELU fused
  g1b[(size_t)wid*64 + lane] = f2bf(vv);
}

// ---------------- GEMM2: h2[N,40] = g1[N,64] @ W2 (bf16 in, fp8 out, stride 64) ----------------
__global__ __launch_bounds__(256) void gemm2_kernel(
    const unsigned short* __restrict__ g1b, const unsigned short* __restrict__ wt2,
    unsigned char* __restrict__ h2f8, int N)
{
  __shared__ unsigned short Alds[64*72];
  const int tid = threadIdx.x;
  const int wv = tid >> 6, lane = tid & 63;
  const int c0 = lane & 15, g = lane >> 4;
  const int rowbase = blockIdx.x * 64;

  const int sr = tid >> 2, sq = tid & 3;
  const int grow = rowbase + sr;
  const bool rv = grow < N;
  uint4 w0 = {0,0,0,0}, w1 = {0,0,0,0};
  if (rv){
    const unsigned short* gp = g1b + (size_t)grow*64 + sq*16;
    w0 = *(const uint4*)gp;
    w1 = *(const uint4*)(gp + 8);
  }
  unsigned short* wls = Alds + sr*72 + sq*16;
  *(uint4*)wls       = w0;
  *(uint4*)(wls + 8) = w1;
  __syncthreads();

  f32x4 acc[3];
  acc[0] = acc[1] = acc[2] = (f32x4){0.f,0.f,0.f,0.f};
  #pragma unroll
  for (int t2 = 0; t2 < 2; ++t2){
    const unsigned short* ap = Alds + (wv*16 + c0)*72 + t2*32 + g*8;
    bf16x8 a = *(const bf16x8*)ap;
    #pragma unroll
    for (int nf = 0; nf < 3; ++nf){
      bf16x8 b = *(const bf16x8*)(wt2 + (nf*16 + c0)*64 + t2*32 + g*8);
      acc[nf] = __builtin_amdgcn_mfma_f32_16x16x32_bf16(a, b, acc[nf], 0,0,0);
    }
  }
  #pragma unroll
  for (int nf = 0; nf < 3; ++nf){
    int col = nf*16 + c0;
    #pragma unroll
    for (int i = 0; i < 4; ++i){
      int row = rowbase + wv*16 + 4*g + i;
      if (row < N && col < 40) h2f8[(size_t)row*64 + col] = f2e4m3(acc[nf][i]);
    }
  }
}

// ---------------- attn2 ----------------
__global__ void attn2_kernel(const unsigned char* __restrict__ h2f8,
    const float* __restrict__ aw_s, const float* __restrict__ aw_d,
    float* __restrict__ as2, float* __restrict__ ad2, int N)
{
  int tid = threadIdx.x;
  int wv = blockIdx.x*4 + (tid >> 6);
  int lane = tid & 63;
  int n = wv*8 + (lane >> 3);
  int cq = (lane & 7)*5;
  float s = 0.f, d = 0.f;
  if (n < N){
    const unsigned char* hp = h2f8 + (size_t)n*64 + cq;
    #pragma unroll
    for (int j = 0; j < 5; ++j){
      float hv = e4m32f(hp[j]);
      s += hv * aw_s[cq + j];
      d += hv * aw_d[cq + j];
    }
  }
  s += __shfl_xor(s, 1); s += __shfl_xor(s, 2); s += __shfl_xor(s, 4);
  d += __shfl_xor(d, 1); d += __shfl_xor(d, 2); d += __shfl_xor(d, 4);
  if (n < N && (lane & 7) == 0){ as2[n] = s; ad2[n] = d; }
}

// ---------------- layer-2 aggregation + bias + log_softmax ----------------
__global__ void l2agg_kernel(const int* __restrict__ rowstart, const int* __restrict__ csr,
    const float* __restrict__ as2, const float* __restrict__ ad2,
    const unsigned char* __restrict__ h2f8, const float* __restrict__ b2,
    float* __restrict__ out, int N)
{
  int wid = blockIdx.x*4 + (threadIdx.x >> 6);
  if (wid >= N) return;
  const int lane = threadIdx.x & 63;
  const bool act = lane < 40;
  int r0 = rowstart[wid], r1 = rowstart[wid+1];
  int cnt = r1 - r0;
  int cap = cnt < 64 ? cnt : 64;
  float adv = ad2[wid];

  int myidx = csr[r0 + (lane < cap ? lane : cap-1)];

  float t = as2[myidx] + adv;
  t = (t > 0.f) ? t : LR_SLOPE*t;
  float w = __expf(t);
  if (lane >= cap) w = 0.f;
  float den = w;
  #pragma unroll
  for (int off = 32; off; off >>= 1) den += __shfl_xor(den, off);

  float acc = 0.f;
  for (int c = 0; c < cap; c += 8){
    #pragma unroll
    for (int j = 0; j < 8; ++j){
      if (c + j < cap){                            // wave-uniform guard
        float wj = __shfl(w, c + j);
        int   sj = __shfl(myidx, c + j);
        float vj = act ? e4m32f(h2f8[(size_t)sj*64 + lane]) : 0.f;
        acc = fmaf(wj, vj, acc);
      }
    }
  }
  for (int r = r0 + 64; r < r1; ++r){             // degree>64 fallback
    int sx = csr[r];
    float tt = as2[sx] + adv;
    tt = (tt > 0.f) ? tt : LR_SLOPE*tt;
    float ww = __expf(tt);
    den += ww;
    if (act) acc = fmaf(ww, e4m32f(h2f8[(size_t)sx*64 + lane]), acc);
  }

  float v = act ? (acc/den + b2[lane]) : -1e30f;
  float m = v;
  #pragma unroll
  for (int off = 32; off; off >>= 1) m = fmaxf(m, __shfl_xor(m, off));
  float ex = act ? __expf(v - m) : 0.f;
  float sum = ex;
  #pragma unroll
  for (int off = 32; off; off >>= 1) sum += __shfl_xor(sum, off);
  if (act) out[(size_t)wid*40 + lane] = v - m - __logf(sum);
}

// ---------------- host ----------------
extern "C" void kernel_launch(void* const* d_in, const int* in_sizes, int n_in,
                              void* d_out, int out_size, void* d_ws, size_t ws_size,
                              hipStream_t stream)
{
  const float* x   = (const float*)d_in[0];
  const int*   ei  = (const int*)d_in[1];
  const float* W1  = (const float*)d_in[2];
  const float* aS1 = (const float*)d_in[3];
  const float* aD1 = (const float*)d_in[4];
  const float* b1  = (const float*)d_in[5];
  const float* W2  = (const float*)d_in[6];
  const float* aS2 = (const float*)d_in[7];
  const float* aD2 = (const float*)d_in[8];
  const float* b2  = (const float*)d_in[9];

  const int N   = in_sizes[0] / 512;
  const int E   = in_sizes[1] / 2;
  const int M   = E + N;
  const int NB  = (N + 1023) >> 10;
  const int NBK = (N + 511) >> 9;

  char* base = (char*)d_ws;
  size_t off = 0;
  auto alloc = [&](size_t bytes)->char* {
    char* p = base + off;
    off += (bytes + 255) & ~(size_t)255;
    return p;
  };
  unsigned char*  h1f8 = (unsigned char*)alloc((size_t)N*64);    // fp8, 64B-aligned rows
  unsigned short* g1b  = (unsigned short*)alloc((size_t)N*64*2);
  float* as1      = (float*)alloc((size_t)N*8*4);
  float* ad1      = (float*)alloc((size_t)N*8*4);
  int*   deg      = (int*)alloc((size_t)N*4);
  int*   rowstart = (int*)alloc((size_t)(N+1)*4);
  int*   bcur     = (int*)alloc((size_t)NBKMAX*4);
  int*   csr      = (int*)alloc((size_t)M*4);
  int*   partial  = (int*)alloc(1024);
  unsigned short* wt1 = (unsigned short*)alloc(64*512*2);
  unsigned short* wt2 = (unsigned short*)alloc(48*64*2);
  // aliases: bucketed (M*4 <= N*128) in g1b's buffer (dead until l1agg);
  // h2f8/as2/ad2 reuse layer-1 buffers (dead after l1agg).
  unsigned* bucketed = (unsigned*)g1b;
  unsigned char* h2f8 = h1f8;                     // N*64 bytes, same size
  float* as2 = as1;
  float* ad2 = ad1;
  float* outp = (float*)d_out;

  prep_w1_kernel<<<128, 256, 0, stream>>>(W1, wt1);
  prep_w2_kernel<<<12, 256, 0, stream>>>(W2, wt2);
  gemm1_kernel<<<(N+63)/64, 256, 0, stream>>>(x, wt1, h1f8, N);
  attn1_kernel<<<(N*8+255)/256, 256, 0, stream>>>(h1f8, aS1, aD1, as1, ad1, N);
  init_deg_kernel<<<(N+255)/256, 256, 0, stream>>>(deg, N);
  hist_kernel<<<(E+255)/256, 256, 0, stream>>>(ei, deg, E);
  scan1_kernel<<<NB, 256, 0, stream>>>(deg, rowstart, partial, N);
  scan2_kernel<<<1, 128, 0, stream>>>(partial, NB);
  scan3_kernel<<<(N+255)/256, 256, 0, stream>>>(rowstart, partial, N, NB);
  init_bcur_kernel<<<1, 256, 0, stream>>>(rowstart, bcur, NBK);
  bucketA_kernel<<<(M+2047)/2048, 256, 0, stream>>>(ei, bcur, bucketed, E, M, NBK);
  bucketB_kernel<<<NBK, 512, 0, stream>>>(bucketed, rowstart, csr, N);
  l1agg_kernel<<<(N+3)/4, 256, 0, stream>>>(rowstart, csr, as1, ad1, h1f8, b1, g1b, N);
  gemm2_kernel<<<(N+63)/64, 256, 0, stream>>>(g1b, wt2, h2f8, N);
  attn2_kernel<<<(N*8+255)/256, 256, 0, stream>>>(h2f8, aS2, aD2, as2, ad2, N);
  l2agg_kernel<<<(N+3)/4, 256, 0, stream>>>(rowstart, csr, as2, ad2, h2f8, b2, outp, N);
}

// Round 5
// 389.766 us; speedup vs baseline: 1.0540x; 1.0540x over previous
//
#include <hip/hip_runtime.h>
#include <hip/hip_bf16.h>

typedef __bf16 bf16x8 __attribute__((ext_vector_type(8)));
typedef float f32x4 __attribute__((ext_vector_type(4)));

#define LR_SLOPE 0.2f
#define NBKMAX 256          // buckets of 512 nodes -> supports N <= 131072

static __device__ __forceinline__ unsigned short f2bf(float f){
  union { float f; unsigned u; } v; v.f = f;
  unsigned u = v.u;
  u += 0x7fffu + ((u >> 16) & 1u);
  return (unsigned short)(u >> 16);
}
static __device__ __forceinline__ unsigned pk2(float a, float b){
  return (unsigned)f2bf(a) | ((unsigned)f2bf(b) << 16);
}
// OCP e4m3 via gfx950 HW converts
static __device__ __forceinline__ unsigned char f2e4m3(float f){
  return (unsigned char)(__builtin_amdgcn_cvt_pk_fp8_f32(f, 0.f, 0, false) & 0xff);
}
static __device__ __forceinline__ float e4m32f(unsigned b){
  return __builtin_amdgcn_cvt_f32_fp8(b, 0);
}

// ---------------- weight prep: transpose + bf16 ----------------
__global__ void prep_w1_kernel(const float* __restrict__ W1, unsigned short* __restrict__ wt1){
  int t = blockIdx.x*256 + threadIdx.x;
  if (t >= 512*64) return;
  int k = t >> 6, n = t & 63;
  wt1[n*512 + k] = f2bf(W1[t]);
}

__global__ void prep_w2_kernel(const float* __restrict__ W2, unsigned short* __restrict__ wt2){
  int t = blockIdx.x*256 + threadIdx.x;
  if (t >= 48*64) return;
  int c = t >> 6, k = t & 63;
  wt2[t] = (c < 40) ? f2bf(W2[k*40 + c]) : (unsigned short)0;
}

// ---------------- GEMM1: h1[N,64] = x[N,512] @ W1 (bf16 MFMA, split fp8 out) ----------------
__global__ __launch_bounds__(256) void gemm1_kernel(
    const float* __restrict__ x, const unsigned short* __restrict__ wt1,
    unsigned char* __restrict__ h1lo, unsigned char* __restrict__ h1hi, int N)
{
  __shared__ unsigned short Alds[64*72];
  const int tid = threadIdx.x;
  const int wv = tid >> 6, lane = tid & 63;
  const int c0 = lane & 15, g = lane >> 4;
  const int rowbase = blockIdx.x * 64;

  const int sr = tid >> 2, sq = tid & 3;
  const int grow = rowbase + sr;
  const bool rv = grow < N;
  const float* xp = x + (size_t)grow*512 + sq*16;
  unsigned short* wls = Alds + sr*72 + sq*16;

  f32x4 acc[4];
  acc[0] = acc[1] = acc[2] = acc[3] = (f32x4){0.f,0.f,0.f,0.f};

  const unsigned short* bp0 = wt1 + (size_t)(wv*16 + c0)*512 + g*8;

  for (int kt = 0; kt < 8; ++kt){
    float4 f0 = {0,0,0,0}, f1 = {0,0,0,0}, f2 = {0,0,0,0}, f3 = {0,0,0,0};
    if (rv){
      const float4* p = (const float4*)(xp + kt*64);
      f0 = p[0]; f1 = p[1]; f2 = p[2]; f3 = p[3];
    }
    uint4 w0 = { pk2(f0.x,f0.y), pk2(f0.z,f0.w), pk2(f1.x,f1.y), pk2(f1.z,f1.w) };
    uint4 w1 = { pk2(f2.x,f2.y), pk2(f2.z,f2.w), pk2(f3.x,f3.y), pk2(f3.z,f3.w) };
    if (kt) __syncthreads();
    *(uint4*)wls       = w0;
    *(uint4*)(wls + 8) = w1;
    __syncthreads();
    bf16x8 b0 = *(const bf16x8*)(bp0 + kt*64);
    bf16x8 b1 = *(const bf16x8*)(bp0 + kt*64 + 32);
    #pragma unroll
    for (int mi = 0; mi < 4; ++mi){
      const unsigned short* ap = Alds + (mi*16 + c0)*72 + g*8;
      bf16x8 a0 = *(const bf16x8*)ap;
      bf16x8 a1 = *(const bf16x8*)(ap + 32);
      acc[mi] = __builtin_amdgcn_mfma_f32_16x16x32_bf16(a0, b0, acc[mi], 0,0,0);
      acc[mi] = __builtin_amdgcn_mfma_f32_16x16x32_bf16(a1, b1, acc[mi], 0,0,0);
    }
  }
  unsigned char* dst = (wv < 2) ? h1lo : h1hi;
  const int colh = (wv & 1)*16 + c0;
  #pragma unroll
  for (int mi = 0; mi < 4; ++mi){
    #pragma unroll
    for (int i = 0; i < 4; ++i){
      int row = rowbase + mi*16 + 4*g + i;
      if (row < N) dst[(size_t)row*32 + colh] = f2e4m3(acc[mi][i]);
    }
  }
}

// ---------------- attn1: per (node,head) dot with att vectors ----------------
__global__ void attn1_kernel(const unsigned char* __restrict__ h1lo,
    const unsigned char* __restrict__ h1hi,
    const float* __restrict__ aw_s, const float* __restrict__ aw_d,
    float* __restrict__ as1, float* __restrict__ ad1, int N)
{
  int t = blockIdx.x*256 + threadIdx.x;
  if (t >= N*8) return;
  int h = t & 7, n = t >> 3;
  const unsigned char* base = (h < 4) ? h1lo : h1hi;
  uint2 hv = *(const uint2*)(base + (size_t)n*32 + (h & 3)*8);
  float f[8];
  f[0] = __builtin_amdgcn_cvt_f32_fp8(hv.x, 0);
  f[1] = __builtin_amdgcn_cvt_f32_fp8(hv.x, 1);
  f[2] = __builtin_amdgcn_cvt_f32_fp8(hv.x, 2);
  f[3] = __builtin_amdgcn_cvt_f32_fp8(hv.x, 3);
  f[4] = __builtin_amdgcn_cvt_f32_fp8(hv.y, 0);
  f[5] = __builtin_amdgcn_cvt_f32_fp8(hv.y, 1);
  f[6] = __builtin_amdgcn_cvt_f32_fp8(hv.y, 2);
  f[7] = __builtin_amdgcn_cvt_f32_fp8(hv.y, 3);
  const float* ws = aw_s + h*8;
  const float* wd = aw_d + h*8;
  float s = 0.f, d = 0.f;
  #pragma unroll
  for (int j = 0; j < 8; ++j){
    s = fmaf(f[j], ws[j], s);
    d = fmaf(f[j], wd[j], d);
  }
  as1[t] = s; ad1[t] = d;
}

// ---------------- CSR build: histogram + scan ----------------
__global__ void init_deg_kernel(int* __restrict__ deg, int N){
  int t = blockIdx.x*256 + threadIdx.x;
  if (t < N) deg[t] = 1;
}

__global__ void hist_kernel(const int* __restrict__ ei, int* __restrict__ deg, int E){
  int t = blockIdx.x*256 + threadIdx.x;
  if (t < E) atomicAdd(&deg[ei[E + t]], 1);
}

__global__ void scan1_kernel(const int* __restrict__ deg, int* __restrict__ rowstart,
                             int* __restrict__ partial, int N){
  __shared__ int sc[256];
  int t = threadIdx.x;
  int base = blockIdx.x*1024 + t*4;
  int d0=0,d1=0,d2=0,d3=0;
  if (base + 3 < N){
    int4 v = *(const int4*)(deg + base);
    d0=v.x; d1=v.y; d2=v.z; d3=v.w;
  } else {
    if (base   < N) d0 = deg[base];
    if (base+1 < N) d1 = deg[base+1];
    if (base+2 < N) d2 = deg[base+2];
    if (base+3 < N) d3 = deg[base+3];
  }
  int s = d0+d1+d2+d3;
  sc[t] = s; __syncthreads();
  for (int off = 1; off < 256; off <<= 1){
    int v = (t >= off) ? sc[t-off] : 0;
    __syncthreads();
    if (t >= off) sc[t] += v;
    __syncthreads();
  }
  int excl = sc[t] - s;
  if (base   < N) rowstart[base]   = excl;
  if (base+1 < N) rowstart[base+1] = excl + d0;
  if (base+2 < N) rowstart[base+2] = excl + d0 + d1;
  if (base+3 < N) rowstart[base+3] = excl + d0 + d1 + d2;
  if (t == 255) partial[blockIdx.x] = sc[255];
}

__global__ void scan2_kernel(int* __restrict__ partial, int NB){
  __shared__ int sc[128];
  int t = threadIdx.x;
  int v = (t < NB) ? partial[t] : 0;
  sc[t] = v; __syncthreads();
  for (int off = 1; off < 128; off <<= 1){
    int u = (t >= off) ? sc[t-off] : 0;
    __syncthreads();
    if (t >= off) sc[t] += u;
    __syncthreads();
  }
  if (t < NB) partial[t] = sc[t] - v;
  if (t == 127) partial[NB] = sc[127];
}

__global__ void scan3_kernel(int* __restrict__ rowstart,
                             const int* __restrict__ partial, int N, int NB){
  int t = blockIdx.x*256 + threadIdx.x;
  if (t < N) rowstart[t] = rowstart[t] + partial[t >> 10];
  if (t == 0) rowstart[N] = partial[NB];
}

__global__ void init_bcur_kernel(const int* __restrict__ rowstart, int* __restrict__ bcur, int NBK){
  int t = threadIdx.x;
  if (t < NBK) bcur[t] = rowstart[t << 9];
}

// ---------------- bucket phase A ----------------
__global__ __launch_bounds__(256) void bucketA_kernel(
    const int* __restrict__ ei, int* __restrict__ bcur,
    unsigned* __restrict__ bucketed, int E, int M, int NBK)
{
  __shared__ int hist[NBKMAX];
  __shared__ int gb[NBKMAX];
  const int tid = threadIdx.x;
  const int t0 = blockIdx.x * 2048;
  for (int i = tid; i < NBK; i += 256) hist[i] = 0;
  __syncthreads();

  unsigned pe[8]; int bk[8], rnk[8];
  #pragma unroll
  for (int j = 0; j < 8; ++j){
    int m = t0 + j*256 + tid;
    if (m < M){
      int s, d;
      if (m < E){ s = ei[m]; d = ei[E + m]; }
      else      { s = d = m - E; }
      bk[j] = d >> 9;
      pe[j] = ((unsigned)s << 9) | (unsigned)(d & 511);
      rnk[j] = atomicAdd(&hist[bk[j]], 1);
    } else bk[j] = -1;
  }
  __syncthreads();
  for (int i = tid; i < NBK; i += 256) gb[i] = atomicAdd(&bcur[i], hist[i]);
  __syncthreads();
  #pragma unroll
  for (int j = 0; j < 8; ++j){
    if (bk[j] >= 0) bucketed[gb[bk[j]] + rnk[j]] = pe[j];
  }
}

// ---------------- bucket phase B ----------------
__global__ __launch_bounds__(512) void bucketB_kernel(
    const unsigned* __restrict__ bucketed, const int* __restrict__ rowstart,
    int* __restrict__ csr, int N)
{
  __shared__ int cur[512];
  const int k = blockIdx.x;
  const int nodebase = k << 9;
  const int nn = min(512, N - nodebase);
  for (int i = threadIdx.x; i < nn; i += 512) cur[i] = rowstart[nodebase + i];
  __syncthreads();
  const int lo = rowstart[nodebase];
  const int hi = rowstart[nodebase + nn];
  for (int m = lo + threadIdx.x; m < hi; m += 512){
    unsigned e = bucketed[m];
    int pos = atomicAdd(&cur[e & 511], 1);
    csr[pos] = (int)(e >> 9);
  }
}

// ---------------- layer-1 aggregation: one feature-half per launch ----------------
// h1h = fp8 [N][32] (this half, 3.2 MB, per-XCD-L2-resident). 2 edges per gather instr.
__global__ void l1agg_pass_kernel(const int* __restrict__ rowstart, const int* __restrict__ csr,
    const float* __restrict__ as1, const float* __restrict__ ad1,
    const unsigned char* __restrict__ h1h, const float* __restrict__ b1,
    unsigned short* __restrict__ g1b, int N, int pass)
{
  int wid = blockIdx.x*4 + (threadIdx.x >> 6);
  if (wid >= N) return;
  const int lane = threadIdx.x & 63;
  const int f    = lane & 31;       // feature within half
  const int par  = lane >> 5;       // edge parity (gather role)
  const int jq   = lane >> 2;       // edge slot 0..15 (weight role)
  const int hq   = lane & 3;        // head-in-half (weight role)
  const int hb   = pass*4;          // head base of this half
  int r0 = rowstart[wid], r1 = rowstart[wid+1];
  int cnt = r1 - r0;
  int cap = cnt < 64 ? cnt : 64;
  float advv = ad1[wid*8 + hb + hq];
  float acc = 0.f, den = 0.f;

  int myidx = csr[r0 + (lane < cap ? lane : cap-1)];

  int sw = __shfl(myidx, jq < cap ? jq : cap-1);
  float ev = as1[sw*8 + hb + hq];

  for (int c = 0; c < cap; c += 16){
    float evn = 0.f;
    if (c + 16 < cap){
      int s2 = c + 16 + jq;
      int swn = __shfl(myidx, s2 < cap ? s2 : cap-1);
      evn = as1[swn*8 + hb + hq];
    }
    float t = ev + advv;
    t = (t > 0.f) ? t : LR_SLOPE*t;
    float w = __expf(t);
    if (c + jq >= cap) w = 0.f;
    den += w;
    #pragma unroll
    for (int j = 0; j < 8; ++j){
      int slot = 2*j + par;
      float wj = __shfl(w, slot*4 + (f >> 3));
      int cs = c + slot;
      int sj = __shfl(myidx, cs < cap ? cs : cap-1);
      acc = fmaf(wj, e4m32f(h1h[(size_t)sj*32 + f]), acc);
    }
    ev = evn;
  }
  for (int r = r0 + 64; r < r1; ++r){             // degree>64 fallback (effectively never)
    int sx = csr[r];
    float t = as1[sx*8 + hb + hq] + advv;
    t = (t > 0.f) ? t : LR_SLOPE*t;
    float w = __expf(t);
    if (jq == 0) den += w;
    float wj = __shfl(w, f >> 3);                 // lanes 0..3 hold classes 0..3
    if (par == 0) acc = fmaf(wj, e4m32f(h1h[(size_t)sx*32 + f]), acc);
  }
  // den: sum over edge slots (lanes sharing lane&3)
  den += __shfl_xor(den, 4);  den += __shfl_xor(den, 8);
  den += __shfl_xor(den, 16); den += __shfl_xor(den, 32);
  float dv = __shfl(den, f >> 3);
  // combine edge parities
  acc += __shfl_xor(acc, 32);
  if (lane < 32){
    float vv = acc/dv + b1[pass*32 + lane];
    vv = (vv > 0.f) ? vv : (__expf(vv) - 1.f);    // ELU fused
    g1b[(size_t)wid*64 + pass*32 + lane] = f2bf(vv);
  }
}

// ---------------- GEMM2: h2[N,40] = g1[N,64] @ W2 (bf16 in, split fp8 out) ----------------
__global__ __launch_bounds__(256) void gemm2_kernel(
    const unsigned short* __restrict__ g1b, const unsigned short* __restrict__ wt2,
    unsigned char* __restrict__ h2a, unsigned char* __restrict__ h2b, int N)
{
  __shared__ unsigned short Alds[64*72];
  const int tid = threadIdx.x;
  const int wv = tid >> 6, lane = tid & 63;
  const int c0 = lane & 15, g = lane >> 4;
  const int rowbase = blockIdx.x * 64;

  const int sr = tid >> 2, sq = tid & 3;
  const int grow = rowbase + sr;
  const bool rv = grow < N;
  uint4 w0 = {0,0,0,0}, w1 = {0,0,0,0};
  if (rv){
    const unsigned short* gp = g1b + (size_t)grow*64 + sq*16;
    w0 = *(const uint4*)gp;
    w1 = *(const uint4*)(gp + 8);
  }
  unsigned short* wls = Alds + sr*72 + sq*16;
  *(uint4*)wls       = w0;
  *(uint4*)(wls + 8) = w1;
  __syncthreads();

  f32x4 acc[3];
  acc[0] = acc[1] = acc[2] = (f32x4){0.f,0.f,0.f,0.f};
  #pragma unroll
  for (int t2 = 0; t2 < 2; ++t2){
    const unsigned short* ap = Alds + (wv*16 + c0)*72 + t2*32 + g*8;
    bf16x8 a = *(const bf16x8*)ap;
    #pragma unroll
    for (int nf = 0; nf < 3; ++nf){
      bf16x8 b = *(const bf16x8*)(wt2 + (nf*16 + c0)*64 + t2*32 + g*8);
      acc[nf] = __builtin_amdgcn_mfma_f32_16x16x32_bf16(a, b, acc[nf], 0,0,0);
    }
  }
  #pragma unroll
  for (int nf = 0; nf < 3; ++nf){
    int col = nf*16 + c0;
    #pragma unroll
    for (int i = 0; i < 4; ++i){
      int row = rowbase + wv*16 + 4*g + i;
      if (row < N){
        if (col < 20)      h2a[(size_t)row*20 + col]      = f2e4m3(acc[nf][i]);
        else if (col < 40) h2b[(size_t)row*20 + col - 20] = f2e4m3(acc[nf][i]);
      }
    }
  }
}

// ---------------- attn2 ----------------
__global__ void attn2_kernel(const unsigned char* __restrict__ h2a,
    const unsigned char* __restrict__ h2b,
    const float* __restrict__ aw_s, const float* __restrict__ aw_d,
    float* __restrict__ as2, float* __restrict__ ad2, int N)
{
  int tid = threadIdx.x;
  int wv = blockIdx.x*4 + (tid >> 6);
  int lane = tid & 63;
  int n = wv*8 + (lane >> 3);
  int cq = (lane & 7)*5;
  float s = 0.f, d = 0.f;
  if (n < N){
    const unsigned char* hp = (cq < 20) ? (h2a + (size_t)n*20 + cq)
                                        : (h2b + (size_t)n*20 + cq - 20);
    #pragma unroll
    for (int j = 0; j < 5; ++j){
      float hv = e4m32f(hp[j]);
      s += hv * aw_s[cq + j];
      d += hv * aw_d[cq + j];
    }
  }
  s += __shfl_xor(s, 1); s += __shfl_xor(s, 2); s += __shfl_xor(s, 4);
  d += __shfl_xor(d, 1); d += __shfl_xor(d, 2); d += __shfl_xor(d, 4);
  if (n < N && (lane & 7) == 0){ as2[n] = s; ad2[n] = d; }
}

// ---------------- layer-2 aggregation: one 20-feature half per launch ----------------
// h2h = fp8 [N][20] (2 MB, L2-resident). 3 edges per gather instr.
// pass 0: write raw v(feats 0-19) to out. pass 1: compute feats 20-39, read back
// pass-0 row, full 40-wide log_softmax, write final.
__global__ void l2agg_pass_kernel(const int* __restrict__ rowstart, const int* __restrict__ csr,
    const float* __restrict__ as2, const float* __restrict__ ad2,
    const unsigned char* __restrict__ h2h, const float* __restrict__ b2,
    float* __restrict__ out, int N, int pass)
{
  int wid = blockIdx.x*4 + (threadIdx.x >> 6);
  if (wid >= N) return;
  const int lane = threadIdx.x & 63;
  const int eg = (lane >= 40) ? 2 : (lane >= 20 ? 1 : 0);
  const int f  = lane - eg*20;
  const bool gl = lane < 60;
  int r0 = rowstart[wid], r1 = rowstart[wid+1];
  int cnt = r1 - r0;
  int cap = cnt < 64 ? cnt : 64;
  float adv = ad2[wid];

  int myidx = csr[r0 + (lane < cap ? lane : cap-1)];

  float t = as2[myidx] + adv;
  t = (t > 0.f) ? t : LR_SLOPE*t;
  float w = __expf(t);
  if (lane >= cap) w = 0.f;
  float den = w;
  #pragma unroll
  for (int off = 32; off; off >>= 1) den += __shfl_xor(den, off);

  float acc = 0.f;
  for (int c = 0; c < cap; c += 12){
    #pragma unroll
    for (int j = 0; j < 4; ++j){
      int slot = c + j*3 + eg;
      float wj = __shfl(w, slot < 63 ? slot : 63);
      if (slot >= cap) wj = 0.f;
      int sj = __shfl(myidx, slot < cap ? slot : cap-1);
      float vj = gl ? e4m32f(h2h[(size_t)sj*20 + f]) : 0.f;
      acc = fmaf(wj, vj, acc);
    }
  }
  for (int r = r0 + 64; r < r1; ++r){             // degree>64 fallback
    int sx = csr[r];
    float tt = as2[sx] + adv;
    tt = (tt > 0.f) ? tt : LR_SLOPE*tt;
    float ww = __expf(tt);
    den += ww;
    if (eg == 0) acc = fmaf(ww, e4m32f(h2h[(size_t)sx*20 + f]), acc);
  }
  // combine 3 edge groups (valid in lanes 0..19)
  float a1 = __shfl(acc, (lane + 20) & 63);
  float a2 = __shfl(acc, (lane + 40) & 63);
  float tot = acc + a1 + a2;
  float vhalf = tot/den + b2[pass*20 + (lane < 20 ? lane : 0)];

  if (pass == 0){
    if (lane < 20) out[(size_t)wid*40 + lane] = vhalf;
  } else {
    float vB = __shfl(vhalf, (lane >= 20 && lane < 40) ? lane - 20 : 0);
    float vA = (lane < 20) ? out[(size_t)wid*40 + lane] : 0.f;
    float v = (lane < 20) ? vA : ((lane < 40) ? vB : -1e30f);
    float m = v;
    #pragma unroll
    for (int off = 32; off; off >>= 1) m = fmaxf(m, __shfl_xor(m, off));
    float ex = (lane < 40) ? __expf(v - m) : 0.f;
    float sum = ex;
    #pragma unroll
    for (int off = 32; off; off >>= 1) sum += __shfl_xor(sum, off);
    if (lane < 40) out[(size_t)wid*40 + lane] = v - m - __logf(sum);
  }
}

// ---------------- host ----------------
extern "C" void kernel_launch(void* const* d_in, const int* in_sizes, int n_in,
                              void* d_out, int out_size, void* d_ws, size_t ws_size,
                              hipStream_t stream)
{
  const float* x   = (const float*)d_in[0];
  const int*   ei  = (const int*)d_in[1];
  const float* W1  = (const float*)d_in[2];
  const float* aS1 = (const float*)d_in[3];
  const float* aD1 = (const float*)d_in[4];
  const float* b1  = (const float*)d_in[5];
  const float* W2  = (const float*)d_in[6];
  const float* aS2 = (const float*)d_in[7];
  const float* aD2 = (const float*)d_in[8];
  const float* b2  = (const float*)d_in[9];

  const int N   = in_sizes[0] / 512;
  const int E   = in_sizes[1] / 2;
  const int M   = E + N;
  const int NB  = (N + 1023) >> 10;
  const int NBK = (N + 511) >> 9;

  char* base = (char*)d_ws;
  size_t off = 0;
  auto alloc = [&](size_t bytes)->char* {
    char* p = base + off;
    off += (bytes + 255) & ~(size_t)255;
    return p;
  };
  unsigned char*  h1lo = (unsigned char*)alloc((size_t)N*32);   // fp8 feats 0-31
  unsigned char*  h1hi = (unsigned char*)alloc((size_t)N*32);   // fp8 feats 32-63
  unsigned short* g1b  = (unsigned short*)alloc((size_t)N*64*2);
  float* as1      = (float*)alloc((size_t)N*8*4);
  float* ad1      = (float*)alloc((size_t)N*8*4);
  int*   deg      = (int*)alloc((size_t)N*4);
  int*   rowstart = (int*)alloc((size_t)(N+1)*4);
  int*   bcur     = (int*)alloc((size_t)NBKMAX*4);
  int*   csr      = (int*)alloc((size_t)M*4);
  int*   partial  = (int*)alloc(1024);
  unsigned short* wt1 = (unsigned short*)alloc(64*512*2);
  unsigned short* wt2 = (unsigned short*)alloc(48*64*2);
  // aliases: bucketed (M*4 <= N*128) in g1b's buffer (dead until l1agg writes it);
  // h2a/h2b (N*20 <= N*32) reuse h1lo/h1hi (dead after l1agg passes);
  // as2/ad2 reuse as1/ad1.
  unsigned* bucketed = (unsigned*)g1b;
  unsigned char* h2a = h1lo;
  unsigned char* h2b = h1hi;
  float* as2 = as1;
  float* ad2 = ad1;
  float* outp = (float*)d_out;

  prep_w1_kernel<<<128, 256, 0, stream>>>(W1, wt1);
  prep_w2_kernel<<<12, 256, 0, stream>>>(W2, wt2);
  gemm1_kernel<<<(N+63)/64, 256, 0, stream>>>(x, wt1, h1lo, h1hi, N);
  attn1_kernel<<<(N*8+255)/256, 256, 0, stream>>>(h1lo, h1hi, aS1, aD1, as1, ad1, N);
  init_deg_kernel<<<(N+255)/256, 256, 0, stream>>>(deg, N);
  hist_kernel<<<(E+255)/256, 256, 0, stream>>>(ei, deg, E);
  scan1_kernel<<<NB, 256, 0, stream>>>(deg, rowstart, partial, N);
  scan2_kernel<<<1, 128, 0, stream>>>(partial, NB);
  scan3_kernel<<<(N+255)/256, 256, 0, stream>>>(rowstart, partial, N, NB);
  init_bcur_kernel<<<1, 256, 0, stream>>>(rowstart, bcur, NBK);
  bucketA_kernel<<<(M+2047)/2048, 256, 0, stream>>>(ei, bcur, bucketed, E, M, NBK);
  bucketB_kernel<<<NBK, 512, 0, stream>>>(bucketed, rowstart, csr, N);
  l1agg_pass_kernel<<<(N+3)/4, 256, 0, stream>>>(rowstart, csr, as1, ad1, h1lo, b1, g1b, N, 0);
  l1agg_pass_kernel<<<(N+3)/4, 256, 0, stream>>>(rowstart, csr, as1, ad1, h1hi, b1, g1b, N, 1);
  gemm2_kernel<<<(N+63)/64, 256, 0, stream>>>(g1b, wt2, h2a, h2b, N);
  attn2_kernel<<<(N*8+255)/256, 256, 0, stream>>>(h2a, h2b, aS2, aD2, as2, ad2, N);
  l2agg_pass_kernel<<<(N+3)/4, 256, 0, stream>>>(rowstart, csr, as2, ad2, h2a, b2, outp, N, 0);
  l2agg_pass_kernel<<<(N+3)/4, 256, 0, stream>>>(rowstart, csr, as2, ad2, h2b, b2, outp, N, 1);
}